// Round 6
// baseline (145.985 us; speedup 1.0000x reference)
//
#include <hip/hip_runtime.h>

// B=8, H=W=1024, N=4096, R=8 -> d=17, patch=289, out (B,N,578) f32.
// p1[b,n,j] = img1[b, m1 + j%17 - 8, m0 + j/17 - 8]; p2 likewise with (m2,m3).
// normalize each 289-vector: (p - mean) / (std_ddof1 + 1e-4).
//
// R5 post-mortem: VALU amortization lowered VALUBusy 45->26% with NO time gain
// -> latency-bound on scattered line fills, MSHR-saturated at ~900cyc HBM
// latency (harness memset thrashes LLC between iters; FETCH=90MB proves
// images re-stream from HBM each run). R6 = R4 body (best, ~45us) + Phase 0:
// first 2048 blocks cooperatively STREAM both images (64MB, coalesced) into
// LLC, halving the fill latency the scattered gathers see.

#define IMG_H 1024
#define IMG_W 1024
#define DPATCH 17
#define NPATCH 289
#define RAD 8
#define LROW 20               // LDS row stride (5 float4 chunks, 16B aligned)
#define PLANE (DPATCH * LROW) // 340 floats per patch plane
#define PFBLOCKS 2048         // prefetch blocks; 2048*16KB = 32MB per image

typedef float float4v __attribute__((ext_vector_type(4)));
typedef float float2v __attribute__((ext_vector_type(2)));

__global__ __launch_bounds__(256) void extract_patch_kernel(
    const float* __restrict__ img1,
    const float* __restrict__ img2,
    const int* __restrict__ matches,
    float* __restrict__ out)
{
    // ---- Phase 0: cooperative streaming prefetch of both images into LLC ----
    // Block k < 2048 streams floats [k*4096, k*4096+4095] of img1 and img2:
    // 8 x dwordx4 per thread, lane-contiguous (1KB/inst/wave). Exact cover:
    // 2048 blocks * 4096 = 8M floats = 32MB = full image array (8*1024*1024).
    float4v pf[8];
    const bool do_pf = (blockIdx.x < PFBLOCKS);
    if (do_pf) {
        const size_t base = (size_t)blockIdx.x * 4096 + ((threadIdx.x & 255) << 2);
#pragma unroll
        for (int j = 0; j < 4; ++j) {
            pf[j]     = *(const float4v*)(img1 + base + j * 1024);
            pf[j + 4] = *(const float4v*)(img2 + base + j * 1024);
        }
    }

    // per-wave private transpose buffer: 2 patch planes (2720 B), 4 waves/block
    __shared__ __align__(16) float lds[4][2 * PLANE];

    const int lane  = threadIdx.x & 63;
    // force wave-uniform -> SGPR, so matches read compiles to s_load_dwordx4
    const int wslot = __builtin_amdgcn_readfirstlane(threadIdx.x >> 6);
    const int pair  = blockIdx.x * 4 + wslot;   // b*4096 + n, scalar
    const int b     = pair >> 12;               // scalar

    const int4 mm = *(const int4*)(matches + (size_t)pair * 4); // scalar load
    const int mx1 = mm.x, my1 = mm.y, mx2 = mm.z, my2 = mm.w;

    const size_t ioff = (size_t)b * (IMG_H * IMG_W);
    const float* __restrict__ imgb1 = img1 + ioff;
    const float* __restrict__ imgb2 = img2 + ioff;

    float* __restrict__ lbase = &lds[wslot][0];

    float sA = 0.f, qA = 0.f, sB = 0.f, qB = 0.f;

    // gather one slot u = a*5 + q of one patch: image row my+a-8, cols mx+4q-8..+3
    auto gather = [&](int u, const float* __restrict__ imgp, int mx, int my,
                      float* __restrict__ ldst, float& ssum, float& ssq) {
        const int a  = u / 5;                 // magic-mul
        const int q  = u - a * 5;
        const int iy = my + a - RAD;
        const int cb = mx + (q << 2) - RAD;
        float4v vv = {0.f, 0.f, 0.f, 0.f};
        const bool rowok = ((unsigned)iy < IMG_H);
        if (rowok && cb >= 0 && (cb + 3) < IMG_W) {
            float4v t = *(const float4v*)(imgp + iy * IMG_W + cb);
            vv.x = t.x;
            vv.y = (q < 4) ? t.y : 0.f;       // mask patch-cols > 16 (chunk q=4)
            vv.z = (q < 4) ? t.z : 0.f;
            vv.w = (q < 4) ? t.w : 0.f;
        } else if (rowok) {                   // image col-edge (~2% of patches)
            const float* rp = imgp + iy * IMG_W;
#pragma unroll
            for (int e = 0; e < 4; ++e) {
                const int cp = (q << 2) + e;  // patch col
                const int ix = cb + e;        // image col
                float v = 0.f;
                if (cp <= 16 && (unsigned)ix < IMG_W) v = rp[ix];
                ((float*)&vv)[e] = v;
            }
        }
        *(float4v*)(ldst + a * LROW + (q << 2)) = vv;   // 16B-aligned LDS write
        ssum += (vv.x + vv.y) + (vv.z + vv.w);
        ssq  += (vv.x * vv.x + vv.y * vv.y) + (vv.z * vv.z + vv.w * vv.w);
    };

    // ---- Phase 1: 170 slots over 3 iters (89% lane efficiency) ----
    // iter0: slots 0..63   -> patch1 u=0..63
    gather(lane, imgb1, mx1, my1, lbase, sA, qA);

    // iter1: slots 64..127 -> patch1 u=64..84 (lanes 0..20), patch2 u=0..42
    {
        const int s  = 64 + lane;
        const bool w2 = (s >= 85);
        const int u  = w2 ? s - 85 : s;
        const float* imgp = w2 ? imgb2 : imgb1;
        const int mx = w2 ? mx2 : mx1;
        const int my = w2 ? my2 : my1;
        float ss = 0.f, sq = 0.f;
        gather(u, imgp, mx, my, lbase + (w2 ? PLANE : 0), ss, sq);
        if (w2) { sB += ss; qB += sq; } else { sA += ss; qA += sq; }
    }

    // iter2: slots 128..169 -> patch2 u=43..84 (lanes 0..41)
    if (lane < 42) {
        gather(43 + lane, imgb2, mx2, my2, lbase + PLANE, sB, qB);
    }

    // ---- wave-64 butterfly reduction, both patches (order-independent) ----
#pragma unroll
    for (int off = 32; off > 0; off >>= 1) {
        sA += __shfl_xor(sA, off, 64);
        qA += __shfl_xor(qA, off, 64);
        sB += __shfl_xor(sB, off, 64);
        qB += __shfl_xor(qB, off, 64);
    }

    const float meanA = sA * (1.0f / 289.0f);
    float varA = (qA - 289.0f * meanA * meanA) * (1.0f / 288.0f);
    varA = fmaxf(varA, 0.0f);
    const float invA = 1.0f / (sqrtf(varA) + 1e-4f);

    const float meanB = sB * (1.0f / 289.0f);
    float varB = (qB - 289.0f * meanB * meanB) * (1.0f / 288.0f);
    varB = fmaxf(varB, 0.0f);
    const float invB = 1.0f / (sqrtf(varB) + 1e-4f);

    // NO barrier: buffer is wave-private, DS ops from one wave are in-order.

    // ---- Phase 2: transposed LDS read, coalesced wide stores (578 floats) ----
    // out[j]: which = j>=289; jj = j - 289*which; val = plane[(jj%17)*20 + jj/17]
    float* __restrict__ o = out + (size_t)pair * 578;
#pragma unroll
    for (int k = 0; k < 2; ++k) {
        const int j0 = (k << 8) + (lane << 2);   // 0..511
        float4v st;
#pragma unroll
        for (int e = 0; e < 4; ++e) {
            const int j   = j0 + e;
            const bool w2 = (j >= NPATCH);
            const int jj  = w2 ? j - NPATCH : j;
            const int c   = jj / DPATCH;          // magic-mul
            const int a   = jj - c * DPATCH;
            const float v = lbase[(w2 ? PLANE : 0) + a * LROW + c];
            ((float*)&st)[e] = (v - (w2 ? meanB : meanA)) * (w2 ? invB : invA);
        }
        __builtin_nontemporal_store(st, (float4v*)(o + j0));
    }
    // tail j = 512..577: 66 elements = 33 lanes x dwordx2 (8B-aligned)
    if (lane < 33) {
        const int j0 = 512 + (lane << 1);
        float2v st;
#pragma unroll
        for (int e = 0; e < 2; ++e) {
            const int jj = j0 + e - NPATCH;       // all patch2 (512 >= 289)
            const int c  = jj / DPATCH;
            const int a  = jj - c * DPATCH;
            ((float*)&st)[e] = (lbase[PLANE + a * LROW + c] - meanB) * invB;
        }
        __builtin_nontemporal_store(st, (float2v*)(o + j0));
    }

    // keep the prefetch loads alive (rule #17: ablation-via-skip DCE). By now
    // the loads completed long ago -> no stall on the implied vmcnt wait.
    if (do_pf) {
#pragma unroll
        for (int j = 0; j < 8; ++j) {
            asm volatile("" :: "v"(pf[j]));
        }
    }
}

extern "C" void kernel_launch(void* const* d_in, const int* in_sizes, int n_in,
                              void* d_out, int out_size, void* d_ws, size_t ws_size,
                              hipStream_t stream) {
    const float* img1  = (const float*)d_in[0];
    const float* img2  = (const float*)d_in[1];
    const int* matches = (const int*)d_in[2];
    float* out         = (float*)d_out;

    // one wave per (b,n) pair: 8*4096 = 32768 pairs, 4 waves/block -> 8192 blocks
    const int n_pairs = 8 * 4096;
    dim3 block(256);
    dim3 grid(n_pairs / 4);
    hipLaunchKernelGGL(extract_patch_kernel, grid, block, 0, stream,
                       img1, img2, matches, out);
}